// Round 6
// baseline (156.015 us; speedup 1.0000x reference)
//
#include <hip/hip_runtime.h>
#include <math.h>

#define NQ 12
#define NL 4
#define NC 10
#define NB 512
#define BN_EPS 1e-5f

typedef float v2f __attribute__((ext_vector_type(2)));

// Packed complex 2x2 butterfly. Constants pre-paired:
// c0={m0,m0} c1={-m1,m1} c2={m2,m2} c3={-m3,m3} (row 0), c4..c7 row 1.
__device__ __forceinline__ void bfly(v2f& A, v2f& B,
    v2f c0, v2f c1, v2f c2, v2f c3, v2f c4, v2f c5, v2f c6, v2f c7)
{
    const v2f As = A.yx, Bs = B.yx;
    const v2f An = __builtin_elementwise_fma(c0, A,
                   __builtin_elementwise_fma(c1, As,
                   __builtin_elementwise_fma(c2, B, c3 * Bs)));
    const v2f Bn = __builtin_elementwise_fma(c4, A,
                   __builtin_elementwise_fma(c5, As,
                   __builtin_elementwise_fma(c6, B, c7 * Bs)));
    A = An; B = Bn;
}

// Round-9: single-wave v2 ("no-transpose"). Round-5 showed 125k cy/wave vs
// ~27k issue floor, duty ~20-25%, FETCH_SIZE 437KB (vs 243KB round-0) with
// no new data reads -> code streaming: the unrolled layer body (~35-60KB)
// exceeds the 32KB L1I and re-streams every layer. Fix: fixed layout
// (reg = amp bits 11..6, lane = amp bits 5..0), so
//  - 6 reg-bit gates/layer: unrolled register butterflies (12KB),
//  - 6 lane-bit gates/layer: ONE rolled loop using ds_bpermute partner
//    fetch (runtime XOR index) + side-selected coefficients (~4KB total),
//  - CNOT (layers 0-2): single LDS round-trip at suffix-parity addresses
//    j_m = XOR_{n>=m} i_n (m<=10), j_11 = i_11 ^ parity(i)  [HW-verified
//    formula, rounds 3-5], naturally bank-conflict-free,
//  - last CNOT folded into readout signs.
// Hot body ~17KB -> I-cache resident. No T1/T2 transposes, no drains.
__global__ __launch_bounds__(64) void vqc_kernel(
    const float* __restrict__ x, const float* __restrict__ w,
    const float* __restrict__ bias, float* __restrict__ probs)
{
    __shared__ v2f stg[4096];                     // 32 KB, CNOT round-trips only
    __shared__ __align__(16) float gm[48][16];    // 48 gates x 8 paired consts

    const int b = blockIdx.x;
    const int t = threadIdx.x;                    // 0..63 = lane

    // ---- one-time: all 48 fused (Rot * RY) matrices, pre-paired/negated ----
    if (t < 48) {
        const int l = t / NQ, q = t % NQ;
        const float xq = 0.5f * x[b*NQ + q];
        const float cx = cosf(xq), sx = sinf(xq);
        const int wi = (l*NQ + q)*3;
        const float phi = w[wi], tht = w[wi+1], om = w[wi+2];
        const float ct = cosf(0.5f*tht), st = sinf(0.5f*tht);
        const float aa = 0.5f*(phi + om), dd = 0.5f*(phi - om);
        const float ca = cosf(aa), sa = sinf(aa);
        const float cd = cosf(dd), sd = sinf(dd);
        const float u00r =  ca*ct, u00i = -sa*ct;
        const float u01r = -cd*st, u01i = -sd*st;
        const float u10r =  cd*st, u10i = -sd*st;
        const float u11r =  ca*ct, u11i =  sa*ct;
        const float m00r = u00r*cx + u01r*sx, m00i = u00i*cx + u01i*sx;
        const float m01r = u01r*cx - u00r*sx, m01i = u01i*cx - u00i*sx;
        const float m10r = u10r*cx + u11r*sx, m10i = u10i*cx + u11i*sx;
        const float m11r = u11r*cx - u10r*sx, m11i = u11i*cx - u10i*sx;
        float* gp = gm[t];
        gp[0]  =  m00r; gp[1]  = m00r;
        gp[2]  = -m00i; gp[3]  = m00i;
        gp[4]  =  m01r; gp[5]  = m01r;
        gp[6]  = -m01i; gp[7]  = m01i;
        gp[8]  =  m10r; gp[9]  = m10r;
        gp[10] = -m10i; gp[11] = m10i;
        gp[12] =  m11r; gp[13] = m11r;
        gp[14] = -m11i; gp[15] = m11i;
    }
    __syncthreads();   // single-wave block: cheap

    // ---- per-lane constants ----
    const unsigned lane = (unsigned)t;
    const unsigned l0=lane&1u, l1=(lane>>1)&1u, l2=(lane>>2)&1u,
                   l3=(lane>>3)&1u, l4=(lane>>4)&1u, l5=(lane>>5)&1u;
    // suffix parities of lane bits: S_k = XOR_{n=k..5} lane_n;  P(lane) = S0
    const unsigned S5=l5, S4=S5^l4, S3=S4^l3, S2=S3^l2, S1=S2^l1, S0=S1^l0;
    const unsigned Spk = (S5<<5)|(S4<<4)|(S3<<3)|(S2<<2)|(S1<<1)|S0;
    const unsigned SS  = Spk | (S0 << 11);        // lane part of CNOT address

    // ---- registers: amp i = (r<<6)|lane, reg bit k <-> amp bit 6+k ----
    v2f a[64];
    #pragma unroll
    for (int r = 0; r < 64; ++r) a[r] = (v2f){0.f, 0.f};
    if (t == 0) a[0].x = 1.f;

    // Reg-bit gate: register bit kbit, matrix row `row` of gm.
    #define GATEK(row, kbit) { \
        const v2f* cp = (const v2f*)gm[row]; \
        const v2f c0=cp[0],c1=cp[1],c2=cp[2],c3=cp[3], \
                  c4=cp[4],c5=cp[5],c6=cp[6],c7=cp[7]; \
        _Pragma("unroll") \
        for (int r0 = 0; r0 < 64; ++r0) \
            if (!(r0 & (kbit))) bfly(a[r0], a[r0|(kbit)], c0,c1,c2,c3,c4,c5,c6,c7); \
    }

    #pragma unroll 1
    for (int l = 0; l < NL; ++l) {
        const int g0 = l*12;

        // ---- 6 reg gates: reg bit k = amp bit 6+k = qubit 5-k ----
        #pragma unroll
        for (int k = 0; k < 6; ++k) GATEK(g0 + 5 - k, 1<<k)

        // ---- 6 lane gates: lane bit k = amp bit k = qubit 11-k ----
        // Partner via ds_bpermute; per-side coefficient select:
        //   side 0 (holds bit=0 elem): out = c0*a + c1*as + c2*p + c3*ps
        //   side 1 (holds bit=1 elem): out = c6*a + c7*as + c4*p + c5*ps
        #pragma unroll 1
        for (int k = 0; k < 6; ++k) {
            const v2f* cp = (const v2f*)gm[g0 + 11 - k];
            const v2f c0=cp[0],c1=cp[1],c2=cp[2],c3=cp[3],
                      c4=cp[4],c5=cp[5],c6=cp[6],c7=cp[7];
            const bool side = (lane >> k) & 1u;
            const v2f C0 = side ? c6 : c0;
            const v2f C1 = side ? c7 : c1;
            const v2f C2 = side ? c4 : c2;
            const v2f C3 = side ? c5 : c3;
            const int idx = (int)((lane ^ (1u << k)) << 2);
            #pragma unroll
            for (int r = 0; r < 64; ++r) {
                v2f p;
                p.x = __int_as_float(__builtin_amdgcn_ds_bpermute(idx, __float_as_int(a[r].x)));
                p.y = __int_as_float(__builtin_amdgcn_ds_bpermute(idx, __float_as_int(a[r].y)));
                a[r] = __builtin_elementwise_fma(C0, a[r],
                       __builtin_elementwise_fma(C1, a[r].yx,
                       __builtin_elementwise_fma(C2, p, C3 * p.yx)));
            }
        }

        if (l < NL-1) {
            // ---- ring CNOT: LDS round-trip at j = pi(i) ----
            // j bits 0..5 = S_m(lane)^P(r); 6..10 = SR_m(r); 11 = r5^P(r)^P(lane)
            __syncthreads();
            #pragma unroll
            for (int r = 0; r < 64; ++r) {
                const unsigned r5=((unsigned)r>>5)&1u, r4=((unsigned)r>>4)&1u,
                               r3=((unsigned)r>>3)&1u, r2=((unsigned)r>>2)&1u,
                               r1=((unsigned)r>>1)&1u, r0b=(unsigned)r&1u;
                const unsigned sr10 = r4^r5;
                const unsigned sr9  = sr10^r3;
                const unsigned sr8  = sr9^r2;
                const unsigned sr7  = sr8^r1;
                const unsigned Pr   = sr7^r0b;        // parity(r) = SR_6
                const unsigned JJ = (r5<<5)|(sr10<<4)|(sr9<<3)|(sr8<<2)|(sr7<<1)|Pr;
                const unsigned j = (JJ<<6) ^ SS ^ (Pr ? 0x83Fu : 0u);
                stg[j] = a[r];
            }
            __syncthreads();
            #pragma unroll
            for (int r = 0; r < 64; ++r) a[r] = stg[(r<<6) | lane];
        }
    }

    // ---- readout; last ring CNOT folded into signs ----
    // class c reads j_{11-c}:
    //  c0: r5^P(r) (reg) x P(lane)=S0 (lane);  c1..c5: SR_{10..6}(r) pure-reg;
    //  c6..c9: P(r) (reg) x S_{5..2}(lane)
    float fA=0.f, f10=0.f, f9=0.f, f8=0.f, f7=0.f, fPar=0.f;
    #pragma unroll
    for (int r = 0; r < 64; ++r) {
        const float p = a[r].x*a[r].x + a[r].y*a[r].y;
        const unsigned r5=((unsigned)r>>5)&1u, r4=((unsigned)r>>4)&1u,
                       r3=((unsigned)r>>3)&1u, r2=((unsigned)r>>2)&1u,
                       r1=((unsigned)r>>1)&1u, r0b=(unsigned)r&1u;
        const unsigned sr10 = r4^r5, sr9 = sr10^r3, sr8 = sr9^r2,
                       sr7 = sr8^r1, Pr = sr7^r0b;
        fA   += (r5^Pr) ? -p : p;
        f10  += sr10    ? -p : p;
        f9   += sr9     ? -p : p;
        f8   += sr8     ? -p : p;
        f7   += sr7     ? -p : p;
        fPar += Pr      ? -p : p;
    }
    float acc[NC];
    acc[0] = S0 ? -fA : fA;
    acc[1] = f10;
    acc[2] = f9;
    acc[3] = f8;
    acc[4] = f7;
    acc[5] = fPar;
    acc[6] = S5 ? -fPar : fPar;
    acc[7] = S4 ? -fPar : fPar;
    acc[8] = S3 ? -fPar : fPar;
    acc[9] = S2 ? -fPar : fPar;

    #pragma unroll
    for (int off = 32; off >= 1; off >>= 1) {
        #pragma unroll
        for (int c = 0; c < NC; ++c)
            acc[c] += __shfl_down(acc[c], off, 64);
    }
    if (t == 0) {
        float ez[NC];
        float mx = -1e30f;
        #pragma unroll
        for (int c = 0; c < NC; ++c) {
            ez[c] = acc[c] + bias[c];
            mx = fmaxf(mx, ez[c]);
        }
        float sum = 0.f;
        #pragma unroll
        for (int c = 0; c < NC; ++c) { ez[c] = expf(ez[c] - mx); sum += ez[c]; }
        const float inv = 1.f / sum;
        #pragma unroll
        for (int c = 0; c < NC; ++c) probs[b*NC + c] = ez[c] * inv;
    }
}

// BatchNorm1d (training mode, biased var) over the batch dim, in place on d_out.
__global__ __launch_bounds__(256) void bn_kernel(
    float* __restrict__ probs, const float* __restrict__ gamma,
    const float* __restrict__ beta)
{
    const int c = blockIdx.x;
    const int t = threadIdx.x;
    const float v0 = probs[t*NC + c];
    const float v1 = probs[(t + 256)*NC + c];
    float s  = v0 + v1;
    float ss = v0*v0 + v1*v1;
    #pragma unroll
    for (int off = 32; off >= 1; off >>= 1) {
        s  += __shfl_down(s,  off, 64);
        ss += __shfl_down(ss, off, 64);
    }
    __shared__ float sm[8];
    __shared__ float stat[2];
    const int wave = t >> 6, lane = t & 63;
    if (lane == 0) { sm[wave] = s; sm[4 + wave] = ss; }
    __syncthreads();
    if (t == 0) {
        const float S  = sm[0] + sm[1] + sm[2] + sm[3];
        const float SS = sm[4] + sm[5] + sm[6] + sm[7];
        const float mu  = S * (1.f/512.f);
        const float var = SS * (1.f/512.f) - mu*mu;
        stat[0] = mu;
        stat[1] = 1.f / sqrtf(var + BN_EPS);
    }
    __syncthreads();
    const float mu = stat[0], inv = stat[1];
    const float g = gamma[c], bt = beta[c];
    probs[t*NC + c]         = (v0 - mu) * inv * g + bt;
    probs[(t + 256)*NC + c] = (v1 - mu) * inv * g + bt;
}

extern "C" void kernel_launch(void* const* d_in, const int* in_sizes, int n_in,
                              void* d_out, int out_size, void* d_ws, size_t ws_size,
                              hipStream_t stream) {
    const float* x     = (const float*)d_in[0];   // (512, 12)
    const float* w     = (const float*)d_in[1];   // (4, 12, 3)
    const float* bias  = (const float*)d_in[2];   // (10,)
    const float* gamma = (const float*)d_in[3];   // (10,)
    const float* beta  = (const float*)d_in[4];   // (10,)
    float* out = (float*)d_out;                   // (512, 10) float32

    vqc_kernel<<<NB, 64, 0, stream>>>(x, w, bias, out);
    bn_kernel<<<NC, 256, 0, stream>>>(out, gamma, beta);
}

// Round 7
// 115.032 us; speedup vs baseline: 1.3563x; 1.3563x over previous
//
#include <hip/hip_runtime.h>
#include <math.h>

#define NQ 12
#define NL 4
#define NC 10
#define NB 512
#define BN_EPS 1e-5f

typedef float v2f __attribute__((ext_vector_type(2)));

// Packed complex 2x2 butterfly. Constants pre-paired:
// c0={m0,m0} c1={-m1,m1} c2={m2,m2} c3={-m3,m3} (row 0), c4..c7 row 1.
__device__ __forceinline__ void bfly(v2f& A, v2f& B,
    v2f c0, v2f c1, v2f c2, v2f c3, v2f c4, v2f c5, v2f c6, v2f c7)
{
    const v2f As = A.yx, Bs = B.yx;
    const v2f An = __builtin_elementwise_fma(c0, A,
                   __builtin_elementwise_fma(c1, As,
                   __builtin_elementwise_fma(c2, B, c3 * Bs)));
    const v2f Bn = __builtin_elementwise_fma(c4, A,
                   __builtin_elementwise_fma(c5, As,
                   __builtin_elementwise_fma(c6, B, c7 * Bs)));
    A = An; B = Bn;
}

// Round-10: round-0 structure (best verified, vqc ~37us) with the hot code
// shrunk ~15x to fit L1I. Audit showed r0 has ~60k cy/CU unexplained by
// VALU issue (16k) + DS pipe (11k) + barrier latency; the fully-unrolled
// 4-layer body is ~40-60KB vs 32KB L1I (shared by 2 CUs) -> L2 instruction
// re-streaming every layer (invisible in FETCH_SIZE, which is HBM-only).
// Fix: roll the layer loop AND the per-stage 4-gate loop (gates within a
// stage are serially dependent, so no ILP lost); keep the 8-bfly r-loops
// unrolled (register indexing). Addressing/swizzles byte-identical to r0.
__global__ __launch_bounds__(256) void vqc_kernel(
    const float* __restrict__ x, const float* __restrict__ w,
    const float* __restrict__ bias, float* __restrict__ probs)
{
    __shared__ v2f buf[2][4096];                  // 2 x 32 KB staging
    __shared__ __align__(16) float gm[48][16];    // 48 gates x 8 paired consts
    __shared__ float red[4*NC];

    const int b = blockIdx.x;
    const int t = threadIdx.x;

    // ---- one-time: all 48 fused (Rot * RY) matrices, pre-paired/negated ----
    if (t < 48) {
        const int l = t / NQ, q = t % NQ;
        const float xq = 0.5f * x[b*NQ + q];
        const float cx = cosf(xq), sx = sinf(xq);
        const int wi = (l*NQ + q)*3;
        const float phi = w[wi], tht = w[wi+1], om = w[wi+2];
        const float ct = cosf(0.5f*tht), st = sinf(0.5f*tht);
        const float aa = 0.5f*(phi + om), dd = 0.5f*(phi - om);
        const float ca = cosf(aa), sa = sinf(aa);
        const float cd = cosf(dd), sd = sinf(dd);
        const float u00r =  ca*ct, u00i = -sa*ct;
        const float u01r = -cd*st, u01i = -sd*st;
        const float u10r =  cd*st, u10i = -sd*st;
        const float u11r =  ca*ct, u11i =  sa*ct;
        const float m00r = u00r*cx + u01r*sx, m00i = u00i*cx + u01i*sx;
        const float m01r = u01r*cx - u00r*sx, m01i = u01i*cx - u00i*sx;
        const float m10r = u10r*cx + u11r*sx, m10i = u10i*cx + u11i*sx;
        const float m11r = u11r*cx - u10r*sx, m11i = u11i*cx - u10i*sx;
        float* gp = gm[t];
        gp[0]  =  m00r; gp[1]  = m00r;
        gp[2]  = -m00i; gp[3]  = m00i;
        gp[4]  =  m01r; gp[5]  = m01r;
        gp[6]  = -m01i; gp[7]  = m01i;
        gp[8]  =  m10r; gp[9]  = m10r;
        gp[10] = -m10i; gp[11] = m10i;
        gp[12] =  m11r; gp[13] = m11r;
        gp[14] = -m11i; gp[15] = m11i;
    }
    __syncthreads();

    // ---- registers: stage-A layout, global i = (r<<8)|t ----
    v2f a[16];
    #pragma unroll
    for (int r = 0; r < 16; ++r) a[r] = (v2f){0.f, 0.f};
    if (t == 0) a[0].x = 1.f;

    const int tl = t & 15, th4 = t >> 4;
    const int phit = t ^ th4;                       // phi(t)
    const int vAB = (th4 << 8) | (tl ^ (th4 * 17)); // A->B write base
    const int wBC = (tl << 8) | ((th4 ^ tl) * 17);  // B->C write base

    // ---- C->A' (CNOT ring) per-thread constants ----
    const unsigned b0_ = t & 1u, b1_ = (t>>1)&1u, b2_ = (t>>2)&1u, b3_ = (t>>3)&1u,
                   b4_ = (t>>4)&1u, b5_ = (t>>5)&1u, b6_ = (t>>6)&1u, b7_ = (t>>7)&1u;
    const unsigned P7 = b7_, P6 = P7^b6_, P5 = P6^b5_, P4 = P5^b4_,
                   P3 = P4^b3_, P2 = P3^b2_, P1 = P2^b1_, T = P1^b0_;  // Pk = parity(t>>k)
    const unsigned base_j = ((T ^ b7_) << 11) | (P6 << 10) | (P5 << 9) | (P4 << 8)
                          | (P3 << 7) | (P2 << 6) | (P1 << 5) | (T << 4)
                          | (T ? 0xFu : 0u);
    const unsigned rA = (base_j >> 8) & 15u;
    const unsigned tA = base_j & 255u;
    const unsigned baseCA = (rA << 8) | ((tA ^ (tA >> 4)) ^ (rA * 17u));

    // Gates in ascending bit order (1,2,4,8): first gate after a transition
    // needs only a[0],a[1]. Bit (1<<g) -> gm[base+3-g].
    // g-loop ROLLED (unroll 1): gates within a stage are serially dependent,
    // so rolling costs no ILP and cuts code 4x.
    #define STAGE(base) \
        _Pragma("unroll 1") \
        for (int g = 0; g < 4; ++g) { \
            const v2f* cp = (const v2f*)gm[(base) + 3 - g]; \
            const v2f c0=cp[0],c1=cp[1],c2=cp[2],c3=cp[3], \
                      c4=cp[4],c5=cp[5],c6=cp[6],c7=cp[7]; \
            const int bit = 1 << g; \
            _Pragma("unroll") \
            for (int r0 = 0; r0 < 16; ++r0) \
                if (!(r0 & bit)) bfly(a[r0], a[r0|bit], c0,c1,c2,c3,c4,c5,c6,c7); \
        }

    int pb = 0;  // staging buffer parity (runtime: layer loop is rolled)
    #pragma unroll 1
    for (int l = 0; l < NL; ++l) {
        // ---- stage 0: qubits 0..3 ----
        STAGE(l*12)
        // ---- transition A->B (single barrier, double-buffered) ----
        {
            v2f* bp = buf[pb]; pb ^= 1;
            #pragma unroll
            for (int r = 0; r < 16; ++r) bp[vAB ^ (r*17)] = a[r];
            __syncthreads();
            #pragma unroll
            for (int r = 0; r < 16; ++r) a[r] = bp[(r<<8) | (phit ^ (r*17))];
        }

        // ---- stage 1: qubits 4..7 ----
        STAGE(l*12 + 4)
        // ---- transition B->C ----
        {
            v2f* bp = buf[pb]; pb ^= 1;
            #pragma unroll
            for (int r = 0; r < 16; ++r) bp[wBC ^ r] = a[r];
            __syncthreads();
            #pragma unroll
            for (int r = 0; r < 16; ++r) a[r] = bp[(r<<8) | (phit ^ (r*17))];
        }

        // ---- stage 2: qubits 8..11 ----
        STAGE(l*12 + 8)
        if (l < NL-1) {
            // ---- transition C->A' with ring-CNOT permutation fused ----
            v2f* bp = buf[pb]; pb ^= 1;
            #pragma unroll
            for (int r = 0; r < 16; ++r) {
                const unsigned k3 = (r>>3)&1u;
                const unsigned k2 = k3 ^ ((r>>2)&1u);
                const unsigned k1 = k2 ^ ((r>>1)&1u);
                const unsigned k0 = k1 ^ (r&1u);           // = par(r)
                const unsigned K  = (k3<<3)|(k2<<2)|(k1<<1)|k0;
                const unsigned d  = K ^ (k0 * 0x888u);     // compile-time per r
                bp[baseCA ^ d] = a[r];
            }
            __syncthreads();
            #pragma unroll
            for (int r = 0; r < 16; ++r) a[r] = bp[(r<<8) | (phit ^ (r*17))];
        }
    }

    // ---- readout: signs are bits of j = M(i), i = (t<<4)|r ----
    const float S0 = (T ^ b7_) ? -1.f : 1.f;  // j_11 base (flip by par(r))
    const float S1 = P6 ? -1.f : 1.f;         // j_10
    const float S2 = P5 ? -1.f : 1.f;         // j_9
    const float S3 = P4 ? -1.f : 1.f;         // j_8
    const float S4 = P3 ? -1.f : 1.f;         // j_7
    const float S5 = P2 ? -1.f : 1.f;         // j_6
    const float S6 = P1 ? -1.f : 1.f;         // j_5
    const float S7 = T  ? -1.f : 1.f;         // j_4
    const float S8 = T  ? -1.f : 1.f;         // j_3 base (flip by r3)
    const float S9 = T  ? -1.f : 1.f;         // j_2 base (flip by r3^r2)

    float acc[NC];
    #pragma unroll
    for (int c = 0; c < NC; ++c) acc[c] = 0.f;
    #pragma unroll
    for (int r = 0; r < 16; ++r) {
        const float p = a[r].x*a[r].x + a[r].y*a[r].y;
        const int r3 = (r>>3)&1, r2 = (r>>2)&1, r1 = (r>>1)&1, r0b = r&1;
        const int par = r3 ^ r2 ^ r1 ^ r0b;
        acc[0] += (par        ? -S0 : S0) * p;
        acc[1] += S1 * p;
        acc[2] += S2 * p;
        acc[3] += S3 * p;
        acc[4] += S4 * p;
        acc[5] += S5 * p;
        acc[6] += S6 * p;
        acc[7] += S7 * p;
        acc[8] += (r3         ? -S8 : S8) * p;
        acc[9] += ((r3 ^ r2)  ? -S9 : S9) * p;
    }
    #pragma unroll
    for (int off = 32; off >= 1; off >>= 1) {
        #pragma unroll
        for (int c = 0; c < NC; ++c)
            acc[c] += __shfl_down(acc[c], off, 64);
    }
    const int wave = t >> 6, lane = t & 63;
    if (lane == 0) {
        #pragma unroll
        for (int c = 0; c < NC; ++c) red[wave*NC + c] = acc[c];
    }
    __syncthreads();
    if (t == 0) {
        float ez[NC];
        float mx = -1e30f;
        #pragma unroll
        for (int c = 0; c < NC; ++c) {
            ez[c] = red[c] + red[NC + c] + red[2*NC + c] + red[3*NC + c] + bias[c];
            mx = fmaxf(mx, ez[c]);
        }
        float sum = 0.f;
        #pragma unroll
        for (int c = 0; c < NC; ++c) { ez[c] = expf(ez[c] - mx); sum += ez[c]; }
        const float inv = 1.f / sum;
        #pragma unroll
        for (int c = 0; c < NC; ++c) probs[b*NC + c] = ez[c] * inv;
    }
}

// BatchNorm1d (training mode, biased var) over the batch dim, in place on d_out.
__global__ __launch_bounds__(256) void bn_kernel(
    float* __restrict__ probs, const float* __restrict__ gamma,
    const float* __restrict__ beta)
{
    const int c = blockIdx.x;
    const int t = threadIdx.x;
    const float v0 = probs[t*NC + c];
    const float v1 = probs[(t + 256)*NC + c];
    float s  = v0 + v1;
    float ss = v0*v0 + v1*v1;
    #pragma unroll
    for (int off = 32; off >= 1; off >>= 1) {
        s  += __shfl_down(s,  off, 64);
        ss += __shfl_down(ss, off, 64);
    }
    __shared__ float sm[8];
    __shared__ float stat[2];
    const int wave = t >> 6, lane = t & 63;
    if (lane == 0) { sm[wave] = s; sm[4 + wave] = ss; }
    __syncthreads();
    if (t == 0) {
        const float S  = sm[0] + sm[1] + sm[2] + sm[3];
        const float SS = sm[4] + sm[5] + sm[6] + sm[7];
        const float mu  = S * (1.f/512.f);
        const float var = SS * (1.f/512.f) - mu*mu;
        stat[0] = mu;
        stat[1] = 1.f / sqrtf(var + BN_EPS);
    }
    __syncthreads();
    const float mu = stat[0], inv = stat[1];
    const float g = gamma[c], bt = beta[c];
    probs[t*NC + c]         = (v0 - mu) * inv * g + bt;
    probs[(t + 256)*NC + c] = (v1 - mu) * inv * g + bt;
}

extern "C" void kernel_launch(void* const* d_in, const int* in_sizes, int n_in,
                              void* d_out, int out_size, void* d_ws, size_t ws_size,
                              hipStream_t stream) {
    const float* x     = (const float*)d_in[0];   // (512, 12)
    const float* w     = (const float*)d_in[1];   // (4, 12, 3)
    const float* bias  = (const float*)d_in[2];   // (10,)
    const float* gamma = (const float*)d_in[3];   // (10,)
    const float* beta  = (const float*)d_in[4];   // (10,)
    float* out = (float*)d_out;                   // (512, 10) float32

    vqc_kernel<<<NB, 256, 0, stream>>>(x, w, bias, out);
    bn_kernel<<<NC, 256, 0, stream>>>(out, gamma, beta);
}

// Round 8
// 90.213 us; speedup vs baseline: 1.7294x; 1.2751x over previous
//
#include <hip/hip_runtime.h>
#include <math.h>

#define NQ 12
#define NL 4
#define NC 10
#define NB 512
#define BN_EPS 1e-5f

typedef float v2f __attribute__((ext_vector_type(2)));

// Packed complex 2x2 butterfly. Constants pre-paired:
// c0={m0,m0} c1={-m1,m1} c2={m2,m2} c3={-m3,m3} (row 0), c4..c7 row 1.
__device__ __forceinline__ void bfly(v2f& A, v2f& B,
    v2f c0, v2f c1, v2f c2, v2f c3, v2f c4, v2f c5, v2f c6, v2f c7)
{
    const v2f As = A.yx, Bs = B.yx;
    const v2f An = __builtin_elementwise_fma(c0, A,
                   __builtin_elementwise_fma(c1, As,
                   __builtin_elementwise_fma(c2, B, c3 * Bs)));
    const v2f Bn = __builtin_elementwise_fma(c4, A,
                   __builtin_elementwise_fma(c5, As,
                   __builtin_elementwise_fma(c6, B, c7 * Bs)));
    A = An; B = Bn;
}

// Round-11: 7 barrier-phases instead of 23. Phase model (r0/r1/r3): each
// cross-wave LDS phase costs ~3.4-3.7k cy wall regardless of occupancy.
// Fixed layout: lanes = amp bits 0-5, waves = amp bits 6-7, regs = 8-11.
// Per layer: 4 reg-butterflies (qubits 0-3) + 6 lane-gates via DPP /
// ds_swizzle / shfl_xor (r6-verified coefficient formula) + RT1 (LDS
// round-trip bringing amp bits 6,7 = qubits 5,4 into regs) + 2 butterflies
// + RT2 (ring-CNOT permutation, XOR-linear -> write addr = SB ^ SD(r),
// SD compile-time). Last layer: no RT2, CNOT folded into readout signs.
// Swizzle s(i)=i^((i>>4)&15): all RT accesses at the b64 4-way bank floor.
__global__ __launch_bounds__(256) void vqc_kernel(
    const float* __restrict__ x, const float* __restrict__ w,
    const float* __restrict__ bias, float* __restrict__ probs)
{
    __shared__ v2f buf[2][4096];                  // 2 x 32 KB staging
    __shared__ __align__(16) float gm[48][16];    // 48 gates x 8 paired consts
    __shared__ float red[4*NC];

    const int b = blockIdx.x;
    const int t = threadIdx.x;

    // ---- one-time: all 48 fused (Rot * RY) matrices, pre-paired/negated ----
    if (t < 48) {
        const int l = t / NQ, q = t % NQ;
        const float xq = 0.5f * x[b*NQ + q];
        const float cx = cosf(xq), sx = sinf(xq);
        const int wi = (l*NQ + q)*3;
        const float phi = w[wi], tht = w[wi+1], om = w[wi+2];
        const float ct = cosf(0.5f*tht), st = sinf(0.5f*tht);
        const float aa = 0.5f*(phi + om), dd = 0.5f*(phi - om);
        const float ca = cosf(aa), sa = sinf(aa);
        const float cd = cosf(dd), sd = sinf(dd);
        const float u00r =  ca*ct, u00i = -sa*ct;
        const float u01r = -cd*st, u01i = -sd*st;
        const float u10r =  cd*st, u10i = -sd*st;
        const float u11r =  ca*ct, u11i =  sa*ct;
        const float m00r = u00r*cx + u01r*sx, m00i = u00i*cx + u01i*sx;
        const float m01r = u01r*cx - u00r*sx, m01i = u01i*cx - u00i*sx;
        const float m10r = u10r*cx + u11r*sx, m10i = u10i*cx + u11i*sx;
        const float m11r = u11r*cx - u10r*sx, m11i = u11i*cx - u10i*sx;
        float* gp = gm[t];
        gp[0]  =  m00r; gp[1]  = m00r;
        gp[2]  = -m00i; gp[3]  = m00i;
        gp[4]  =  m01r; gp[5]  = m01r;
        gp[6]  = -m01i; gp[7]  = m01i;
        gp[8]  =  m10r; gp[9]  = m10r;
        gp[10] = -m10i; gp[11] = m10i;
        gp[12] =  m11r; gp[13] = m11r;
        gp[14] = -m11i; gp[15] = m11i;
    }
    __syncthreads();

    // ---- per-thread constants ----
    const unsigned u0=t&1u, u1=(t>>1)&1u, u2=(t>>2)&1u, u3=(t>>3)&1u,
                   u4=(t>>4)&1u, u5=(t>>5)&1u;
    const unsigned t6b=(t>>6)&1u, t7b=(t>>7)&1u, w67=t6b^t7b;
    // suffix parities of lane bits t0..t5: q_m = XOR_{n=m..5} t_n
    const unsigned q5=u5, q4=q5^u4, q3=q4^u3, q2=q3^u2, q1=q2^u1, q0=q1^u0;
    const unsigned Pt = q0;
    const unsigned LS = q0|(q1<<1)|(q2<<2)|(q3<<3)|(q4<<4)|(q5<<5);
    // s(i)=i^((i>>4)&15) pieces:
    const unsigned st = (unsigned)t ^ (((unsigned)t>>4)&15u);   // RT1-write low / RT2-read low
    const unsigned rb1 = ((unsigned)t & 63u) | (t6b<<8) | (t7b<<9);
    const unsigned rbase1 = rb1 ^ ((rb1>>4)&15u);               // RT1-read base
    const unsigned Jbase = (LS ^ (w67 ? 63u : 0u))
                         | (w67<<6) | (w67<<7) | (w67<<8) | (t7b<<9)
                         | ((Pt^w67)<<11);
    const unsigned SB = Jbase ^ ((Jbase>>4)&15u);               // RT2-write base

    // compile-time deltas (folded under full unroll)
    #define RD1(r) (((((r)&1)?0x44u:0u))^((((r)&2)?0x88u:0u))^((((r)&4)?0x400u:0u))^((((r)&8)?0x800u:0u)))
    #define JD(r)  (((((r)&1)?0x87Fu:0u))^((((r)&2)?0x8FFu:0u))^((((r)&4)?0xFFFu:0u))^((((r)&8)?0x7FFu:0u)))
    #define SD(r)  (JD(r) ^ ((JD(r)>>4)&15u))

    // ---- registers: layout A, amp i = (r<<8)|t ----
    v2f a[16];
    #pragma unroll
    for (int r = 0; r < 16; ++r) a[r] = (v2f){0.f, 0.f};
    if (t == 0) a[0].x = 1.f;

    // Reg-bit butterfly gate.
    #define GATEK(row, kbit) { \
        const v2f* cp = (const v2f*)gm[row]; \
        const v2f c0=cp[0],c1=cp[1],c2=cp[2],c3=cp[3], \
                  c4=cp[4],c5=cp[5],c6=cp[6],c7=cp[7]; \
        _Pragma("unroll") \
        for (int r0 = 0; r0 < 16; ++r0) \
            if (!(r0 & (kbit))) bfly(a[r0], a[r0|(kbit)], c0,c1,c2,c3,c4,c5,c6,c7); \
    }

    // Lane-bit gate: partner fetch per component, side-selected coeffs
    // (formula correctness-verified in round 6).
    #define LGATE(row, kbit, FX, FY) { \
        const v2f* cp = (const v2f*)gm[row]; \
        const v2f c0=cp[0],c1=cp[1],c2=cp[2],c3=cp[3], \
                  c4=cp[4],c5=cp[5],c6=cp[6],c7=cp[7]; \
        const bool side = ((t >> (kbit)) & 1) != 0; \
        const v2f C0 = side ? c6 : c0, C1 = side ? c7 : c1; \
        const v2f C2 = side ? c4 : c2, C3 = side ? c5 : c3; \
        _Pragma("unroll") \
        for (int r = 0; r < 16; ++r) { \
            v2f p; p.x = (FX); p.y = (FY); \
            a[r] = __builtin_elementwise_fma(C0, a[r], \
                   __builtin_elementwise_fma(C1, a[r].yx, \
                   __builtin_elementwise_fma(C2, p, C3 * p.yx))); \
        } }

    #define DPPF(v, ctrl) __int_as_float(__builtin_amdgcn_update_dpp(0, __float_as_int(v), (ctrl), 0xF, 0xF, true))
    #define SWZF(v, off)  __int_as_float(__builtin_amdgcn_ds_swizzle(__float_as_int(v), (off)))

    int pb = 0;  // folds at compile time (full unroll)
    #pragma unroll
    for (int l = 0; l < NL; ++l) {
        const int g0 = l*12;
        // ---- reg butterflies: qubits 0..3 (amp bits 11..8) ----
        GATEK(g0+3, 1) GATEK(g0+2, 2) GATEK(g0+1, 4) GATEK(g0+0, 8)
        // ---- lane gates: qubit 11-k on lane bit k ----
        LGATE(g0+11, 0, DPPF(a[r].x, 0xB1),  DPPF(a[r].y, 0xB1))   // xor1: quad_perm[1,0,3,2]
        LGATE(g0+10, 1, DPPF(a[r].x, 0x4E),  DPPF(a[r].y, 0x4E))   // xor2: quad_perm[2,3,0,1]
        LGATE(g0+9,  2, SWZF(a[r].x, 0x101F), SWZF(a[r].y, 0x101F))// xor4: ds_swizzle
        LGATE(g0+8,  3, DPPF(a[r].x, 0x128), DPPF(a[r].y, 0x128))  // xor8: row_ror:8
        LGATE(g0+7,  4, SWZF(a[r].x, 0x401F), SWZF(a[r].y, 0x401F))// xor16: ds_swizzle
        LGATE(g0+6,  5, __shfl_xor(a[r].x, 32, 64), __shfl_xor(a[r].y, 32, 64)) // xor32

        // ---- RT1: rotate amp bits {6,7} into regs (layout B) ----
        {
            v2f* bp = buf[pb]; pb ^= 1;
            #pragma unroll
            for (int r = 0; r < 16; ++r) bp[((unsigned)r<<8) | st] = a[r];
            __syncthreads();
            #pragma unroll
            for (int r = 0; r < 16; ++r) a[r] = bp[rbase1 ^ RD1(r)];
        }
        // ---- butterflies on qubits 5,4 (now reg bits 0,1) ----
        GATEK(g0+5, 1) GATEK(g0+4, 2)

        if (l < NL-1) {
            // ---- RT2: ring-CNOT permutation, back to layout A ----
            v2f* bp = buf[pb]; pb ^= 1;
            #pragma unroll
            for (int r = 0; r < 16; ++r) bp[SB ^ SD(r)] = a[r];
            __syncthreads();
            #pragma unroll
            for (int r = 0; r < 16; ++r) a[r] = bp[((unsigned)r<<8) | st];
        }
    }

    // ---- readout from layout B; last ring-CNOT folded into signs ----
    // j = pi(i): per-reg sign groups A: r0^r1^r2, B: r2^r3, C: r1^r2^r3,
    // D: parity(r); thread factors as derived from the linear map.
    float A=0.f, B=0.f, C=0.f, D=0.f;
    #pragma unroll
    for (int r = 0; r < 16; ++r) {
        const float p = a[r].x*a[r].x + a[r].y*a[r].y;
        const int s012 = (r ^ (r>>1) ^ (r>>2)) & 1;
        const int s23  = ((r>>2) ^ (r>>3)) & 1;
        const int s123 = ((r>>1) ^ (r>>2) ^ (r>>3)) & 1;
        const int spar = (r ^ (r>>1) ^ (r>>2) ^ (r>>3)) & 1;
        A += s012 ? -p : p;
        B += s23  ? -p : p;
        C += s123 ? -p : p;
        D += spar ? -p : p;
    }
    float acc[NC];
    acc[0] = (Pt^w67) ? -A : A;
    acc[1] = B;
    acc[2] = t7b      ? -B : B;
    acc[3] = w67      ? -B : B;
    acc[4] = w67      ? -C : C;
    acc[5] = w67      ? -D : D;
    acc[6] = (q5^w67) ? -D : D;
    acc[7] = (q4^w67) ? -D : D;
    acc[8] = (q3^w67) ? -D : D;
    acc[9] = (q2^w67) ? -D : D;

    #pragma unroll
    for (int off = 32; off >= 1; off >>= 1) {
        #pragma unroll
        for (int c = 0; c < NC; ++c)
            acc[c] += __shfl_down(acc[c], off, 64);
    }
    const int wave = t >> 6, lane = t & 63;
    if (lane == 0) {
        #pragma unroll
        for (int c = 0; c < NC; ++c) red[wave*NC + c] = acc[c];
    }
    __syncthreads();
    if (t == 0) {
        float ez[NC];
        float mx = -1e30f;
        #pragma unroll
        for (int c = 0; c < NC; ++c) {
            ez[c] = red[c] + red[NC + c] + red[2*NC + c] + red[3*NC + c] + bias[c];
            mx = fmaxf(mx, ez[c]);
        }
        float sum = 0.f;
        #pragma unroll
        for (int c = 0; c < NC; ++c) { ez[c] = expf(ez[c] - mx); sum += ez[c]; }
        const float inv = 1.f / sum;
        #pragma unroll
        for (int c = 0; c < NC; ++c) probs[b*NC + c] = ez[c] * inv;
    }
}

// BatchNorm1d (training mode, biased var) over the batch dim, in place on d_out.
__global__ __launch_bounds__(256) void bn_kernel(
    float* __restrict__ probs, const float* __restrict__ gamma,
    const float* __restrict__ beta)
{
    const int c = blockIdx.x;
    const int t = threadIdx.x;
    const float v0 = probs[t*NC + c];
    const float v1 = probs[(t + 256)*NC + c];
    float s  = v0 + v1;
    float ss = v0*v0 + v1*v1;
    #pragma unroll
    for (int off = 32; off >= 1; off >>= 1) {
        s  += __shfl_down(s,  off, 64);
        ss += __shfl_down(ss, off, 64);
    }
    __shared__ float sm[8];
    __shared__ float stat[2];
    const int wave = t >> 6, lane = t & 63;
    if (lane == 0) { sm[wave] = s; sm[4 + wave] = ss; }
    __syncthreads();
    if (t == 0) {
        const float S  = sm[0] + sm[1] + sm[2] + sm[3];
        const float SS = sm[4] + sm[5] + sm[6] + sm[7];
        const float mu  = S * (1.f/512.f);
        const float var = SS * (1.f/512.f) - mu*mu;
        stat[0] = mu;
        stat[1] = 1.f / sqrtf(var + BN_EPS);
    }
    __syncthreads();
    const float mu = stat[0], inv = stat[1];
    const float g = gamma[c], bt = beta[c];
    probs[t*NC + c]         = (v0 - mu) * inv * g + bt;
    probs[(t + 256)*NC + c] = (v1 - mu) * inv * g + bt;
}

extern "C" void kernel_launch(void* const* d_in, const int* in_sizes, int n_in,
                              void* d_out, int out_size, void* d_ws, size_t ws_size,
                              hipStream_t stream) {
    const float* x     = (const float*)d_in[0];   // (512, 12)
    const float* w     = (const float*)d_in[1];   // (4, 12, 3)
    const float* bias  = (const float*)d_in[2];   // (10,)
    const float* gamma = (const float*)d_in[3];   // (10,)
    const float* beta  = (const float*)d_in[4];   // (10,)
    float* out = (float*)d_out;                   // (512, 10) float32

    vqc_kernel<<<NB, 256, 0, stream>>>(x, w, bias, out);
    bn_kernel<<<NC, 256, 0, stream>>>(out, gamma, beta);
}